// Round 1
// baseline (386.769 us; speedup 1.0000x reference)
//
#include <hip/hip_runtime.h>
#include <hip/hip_bf16.h>

#define NTOK 8192
#define HDIM 768
#define IDIM 2048
#define NEXP 8
#define BM 128
#define BN 128
#define BK 32
#define LIST_CAP 17408  // sum_e roundup(cnt[e],128) <= 2T + 8*128

// ---- ws layout (byte offsets) ----
#define WS_CNT    0u          // int[8]
#define WS_CNT2   32u         // int[8]
#define WS_OFFP   64u         // int[8]  (128-padded prefix)
#define WS_RUN    96u         // float[8]
#define WS_IMP    256u        // float[128*8] per-block importance partials
#define WS_CNTP   4352u       // int[128*8]   per-block count partials
#define WS_TOPKI  16384u      // int[NTOK*2]
#define WS_TOPKP  81920u      // float[NTOK*2]
#define WS_LTOK   147456u     // int[LIST_CAP]
#define WS_LW     217088u     // float[LIST_CAP]
#define WS_XB     286720u     // ushort bf16 [NTOK*HDIM]
#define WS_W1B    12869632u   // ushort bf16 [NEXP*IDIM*HDIM]
#define WS_W2B    38035456u   // ushort bf16 [NEXP*HDIM*IDIM]
#define WS_H      63201280u   // ushort bf16 [LIST_CAP*IDIM]
#define WS_NEEDED 134504448u

typedef __attribute__((ext_vector_type(8))) __bf16 bf16x8;
typedef __attribute__((ext_vector_type(4))) float f32x4;

__device__ __forceinline__ unsigned short f2bf(float f) {
  unsigned int u = __float_as_uint(f);
  u += 0x7FFFu + ((u >> 16) & 1u);   // RNE (inputs finite, no NaN handling)
  return (unsigned short)(u >> 16);
}

__device__ __forceinline__ void gload_lds16(const void* g, void* l) {
  __builtin_amdgcn_global_load_lds(
      (const __attribute__((address_space(1))) void*)g,
      (__attribute__((address_space(3))) void*)l, 16, 0, 0);
}

// ---------------- fp32 -> bf16 conversion ----------------
__global__ void cvt_kernel(const float* __restrict__ src,
                           unsigned short* __restrict__ dst, int n8) {
  int stride = gridDim.x * blockDim.x;
  const float4* s4 = (const float4*)src;
  uint4* d4 = (uint4*)dst;
  for (int i = blockIdx.x * blockDim.x + threadIdx.x; i < n8; i += stride) {
    float4 a = s4[2 * i];
    float4 b = s4[2 * i + 1];
    uint4 o;
    o.x = (unsigned)f2bf(a.x) | ((unsigned)f2bf(a.y) << 16);
    o.y = (unsigned)f2bf(a.z) | ((unsigned)f2bf(a.w) << 16);
    o.z = (unsigned)f2bf(b.x) | ((unsigned)f2bf(b.y) << 16);
    o.w = (unsigned)f2bf(b.z) | ((unsigned)f2bf(b.w) << 16);
    d4[i] = o;
  }
}

// ---------------- router: logits, softmax, top-2, partials ----------------
__global__ __launch_bounds__(256) void router_kernel(
    const float* __restrict__ x, const float* __restrict__ rw,
    char* __restrict__ ws) {
  __shared__ float rws[NEXP * HDIM];  // 24KB
  __shared__ float lg[64][NEXP];
  const int tid = threadIdx.x;
  const int t0 = blockIdx.x * 64;
  for (int i = tid; i < NEXP * HDIM / 4; i += 256)
    ((float4*)rws)[i] = ((const float4*)rw)[i];
  __syncthreads();
  // 512 (token,expert) dots, 2 per thread, fp32 exact-ish
  for (int p = tid; p < 512; p += 256) {
    const int m = p >> 3, e = p & 7;
    const float* xr = x + (size_t)(t0 + m) * HDIM;
    const float* wr = rws + e * HDIM;
    float acc = 0.f;
    for (int h = 0; h < HDIM; h += 4) {
      float4 xv = *(const float4*)(xr + h);
      acc += xv.x * wr[h] + xv.y * wr[h + 1] + xv.z * wr[h + 2] + xv.w * wr[h + 3];
    }
    lg[m][e] = acc;
  }
  __syncthreads();
  if (tid < 64) {  // one wave: softmax + top2 + deterministic partials
    const int m = tid;
    float pr[8], mx = -1e30f;
    for (int e = 0; e < 8; e++) { pr[e] = lg[m][e]; mx = fmaxf(mx, pr[e]); }
    float s = 0.f;
    for (int e = 0; e < 8; e++) { pr[e] = __expf(pr[e] - mx); s += pr[e]; }
    float inv = 1.f / s;
    for (int e = 0; e < 8; e++) pr[e] *= inv;
    int i0 = 0;
    for (int e = 1; e < 8; e++) if (pr[e] > pr[i0]) i0 = e;   // ties: lowest idx
    int i1 = (i0 == 0) ? 1 : 0;
    for (int e = 0; e < 8; e++) if (e != i0 && pr[e] > pr[i1]) i1 = e;
    const int t = t0 + m;
    ((int*)(ws + WS_TOPKI))[2 * t] = i0;
    ((int*)(ws + WS_TOPKI))[2 * t + 1] = i1;
    ((float*)(ws + WS_TOPKP))[2 * t] = pr[i0];
    ((float*)(ws + WS_TOPKP))[2 * t + 1] = pr[i1];
    float* ip = (float*)(ws + WS_IMP) + blockIdx.x * 8;
    int* cp = (int*)(ws + WS_CNTP) + blockIdx.x * 8;
    for (int e = 0; e < 8; e++) {
      float v = pr[e];
      for (int off = 32; off; off >>= 1) v += __shfl_down(v, off);
      unsigned long long b0 = __ballot(i0 == e);
      unsigned long long b1 = __ballot(i1 == e);
      if (tid == 0) { ip[e] = v; cp[e] = __popcll(b0) + __popcll(b1); }
    }
  }
}

// ---------------- finalize: running[], counts, padded prefix ----------------
__global__ void finalize_kernel(char* __restrict__ ws) {
  const int tid = threadIdx.x;
  if (tid < 8) {
    float s = 0.f; int c = 0;
    const float* ip = (const float*)(ws + WS_IMP);
    const int* cp = (const int*)(ws + WS_CNTP);
    for (int b = 0; b < 128; b++) { s += ip[b * 8 + tid]; c += cp[b * 8 + tid]; }
    float running = 1.0f;
    float blended = running + 0.1f * (s - running);
    ((float*)(ws + WS_RUN))[tid] = blended + 0.01f;
    ((int*)(ws + WS_CNT))[tid] = c;
    ((int*)(ws + WS_CNT2))[tid] = 0;
  }
  __syncthreads();
  if (tid == 0) {
    const int* cnt = (const int*)(ws + WS_CNT);
    int* offp = (int*)(ws + WS_OFFP);
    int o = 0;
    for (int e = 0; e < 8; e++) { offp[e] = o; o += (cnt[e] + BM - 1) / BM * BM; }
  }
}

// ---------------- build per-expert lists + combine weights ----------------
__global__ void build_lists(char* __restrict__ ws) {
  const int t = blockIdx.x * blockDim.x + threadIdx.x;
  if (t >= NTOK) return;
  const int* ti = (const int*)(ws + WS_TOPKI);
  const float* tp = (const float*)(ws + WS_TOPKP);
  const float* run = (const float*)(ws + WS_RUN);
  int* cnt2 = (int*)(ws + WS_CNT2);
  const int* offp = (const int*)(ws + WS_OFFP);
  int* ltok = (int*)(ws + WS_LTOK);
  float* lw = (float*)(ws + WS_LW);
  const int e0 = ti[2 * t], e1 = ti[2 * t + 1];
  const float b0 = tp[2 * t] / run[e0], b1 = tp[2 * t + 1] / run[e1];
  const float inv = 1.f / (b0 + b1);
  int s0 = atomicAdd(&cnt2[e0], 1);
  int g0 = offp[e0] + s0; ltok[g0] = t; lw[g0] = b0 * inv;
  int s1 = atomicAdd(&cnt2[e1], 1);
  int g1 = offp[e1] + s1; ltok[g1] = t; lw[g1] = b1 * inv;
}

// ---------------- GEMM1: h = silu(x_gather @ w1_e^T), K=768 ----------------
__global__ __launch_bounds__(256) void gemm1_kernel(char* __restrict__ ws) {
  __shared__ unsigned short As[BM * BK];
  __shared__ unsigned short Bs[BN * BK];
  const int e = blockIdx.z;
  const int ce = ((const int*)(ws + WS_CNT))[e];
  const int rt = blockIdx.y;
  if (rt * BM >= ce) return;
  const int base = ((const int*)(ws + WS_OFFP))[e];
  const int* __restrict__ ltok = (const int*)(ws + WS_LTOK);
  const unsigned short* __restrict__ xb = (const unsigned short*)(ws + WS_XB);
  const unsigned short* __restrict__ w1b =
      (const unsigned short*)(ws + WS_W1B) + (size_t)e * IDIM * HDIM;
  unsigned short* __restrict__ hb = (unsigned short*)(ws + WS_H);

  const int tid = threadIdx.x;
  const int lane = tid & 63, wave = tid >> 6;
  const int r0 = tid >> 2, ko = (tid & 3) * 8, r1 = r0 + 64;

  int s0 = rt * BM + r0; s0 = (s0 < ce) ? s0 : (ce - 1);
  int s1 = rt * BM + r1; s1 = (s1 < ce) ? s1 : (ce - 1);
  const unsigned short* ga0 = xb + (size_t)ltok[base + s0] * HDIM + ko;
  const unsigned short* ga1 = xb + (size_t)ltok[base + s1] * HDIM + ko;
  const int n0 = blockIdx.x * BN;
  const unsigned short* gb0 = w1b + (size_t)(n0 + r0) * HDIM + ko;
  const unsigned short* gb1 = w1b + (size_t)(n0 + r1) * HDIM + ko;

  unsigned short* lA0 = As + wave * 512;
  unsigned short* lA1 = As + 2048 + wave * 512;
  unsigned short* lB0 = Bs + wave * 512;
  unsigned short* lB1 = Bs + 2048 + wave * 512;

  f32x4 acc[4][4];
#pragma unroll
  for (int i = 0; i < 4; i++)
#pragma unroll
    for (int j = 0; j < 4; j++) acc[i][j] = (f32x4){0.f, 0.f, 0.f, 0.f};

  const int wr = (wave >> 1) * 64, wc = (wave & 1) * 64;
  const int fr = lane & 15, kq = (lane >> 4) * 8;

  for (int kb = 0; kb < HDIM; kb += BK) {
    gload_lds16(ga0 + kb, lA0);
    gload_lds16(ga1 + kb, lA1);
    gload_lds16(gb0 + kb, lB0);
    gload_lds16(gb1 + kb, lB1);
    __syncthreads();
    bf16x8 af[4], bg[4];
#pragma unroll
    for (int i = 0; i < 4; i++) af[i] = *(const bf16x8*)&As[(wr + i * 16 + fr) * BK + kq];
#pragma unroll
    for (int j = 0; j < 4; j++) bg[j] = *(const bf16x8*)&Bs[(wc + j * 16 + fr) * BK + kq];
#pragma unroll
    for (int i = 0; i < 4; i++)
#pragma unroll
      for (int j = 0; j < 4; j++)
        acc[i][j] = __builtin_amdgcn_mfma_f32_16x16x32_bf16(af[i], bg[j], acc[i][j], 0, 0, 0);
    __syncthreads();
  }

  const int rq = (lane >> 4) * 4;
#pragma unroll
  for (int i = 0; i < 4; i++) {
#pragma unroll
    for (int r = 0; r < 4; r++) {
      const int slot = rt * BM + wr + i * 16 + rq + r;
      unsigned short* hrow = hb + (size_t)(base + slot) * IDIM + n0 + wc;
#pragma unroll
      for (int j = 0; j < 4; j++) {
        float v = acc[i][j][r];
        float sv = v / (1.f + __expf(-v));
        hrow[j * 16 + fr] = f2bf(sv);
      }
    }
  }
}

// ---------------- GEMM2: out += w * (h @ w2_e^T), K=2048 ----------------
__global__ __launch_bounds__(256) void gemm2_kernel(char* __restrict__ ws,
                                                    float* __restrict__ out) {
  __shared__ unsigned short As[BM * BK];
  __shared__ unsigned short Bs[BN * BK];
  const int e = blockIdx.z;
  const int ce = ((const int*)(ws + WS_CNT))[e];
  const int rt = blockIdx.y;
  if (rt * BM >= ce) return;
  const int base = ((const int*)(ws + WS_OFFP))[e];
  const int* __restrict__ ltok = (const int*)(ws + WS_LTOK);
  const float* __restrict__ lw = (const float*)(ws + WS_LW);
  const unsigned short* __restrict__ hb = (const unsigned short*)(ws + WS_H);
  const unsigned short* __restrict__ w2b =
      (const unsigned short*)(ws + WS_W2B) + (size_t)e * HDIM * IDIM;

  const int tid = threadIdx.x;
  const int lane = tid & 63, wave = tid >> 6;
  const int r0 = tid >> 2, ko = (tid & 3) * 8, r1 = r0 + 64;

  const unsigned short* ga0 = hb + (size_t)(base + rt * BM + r0) * IDIM + ko;
  const unsigned short* ga1 = hb + (size_t)(base + rt * BM + r1) * IDIM + ko;
  const int n0 = blockIdx.x * BN;
  const unsigned short* gb0 = w2b + (size_t)(n0 + r0) * IDIM + ko;
  const unsigned short* gb1 = w2b + (size_t)(n0 + r1) * IDIM + ko;

  unsigned short* lA0 = As + wave * 512;
  unsigned short* lA1 = As + 2048 + wave * 512;
  unsigned short* lB0 = Bs + wave * 512;
  unsigned short* lB1 = Bs + 2048 + wave * 512;

  f32x4 acc[4][4];
#pragma unroll
  for (int i = 0; i < 4; i++)
#pragma unroll
    for (int j = 0; j < 4; j++) acc[i][j] = (f32x4){0.f, 0.f, 0.f, 0.f};

  const int wr = (wave >> 1) * 64, wc = (wave & 1) * 64;
  const int fr = lane & 15, kq = (lane >> 4) * 8;

  for (int kb = 0; kb < IDIM; kb += BK) {
    gload_lds16(ga0 + kb, lA0);
    gload_lds16(ga1 + kb, lA1);
    gload_lds16(gb0 + kb, lB0);
    gload_lds16(gb1 + kb, lB1);
    __syncthreads();
    bf16x8 af[4], bg[4];
#pragma unroll
    for (int i = 0; i < 4; i++) af[i] = *(const bf16x8*)&As[(wr + i * 16 + fr) * BK + kq];
#pragma unroll
    for (int j = 0; j < 4; j++) bg[j] = *(const bf16x8*)&Bs[(wc + j * 16 + fr) * BK + kq];
#pragma unroll
    for (int i = 0; i < 4; i++)
#pragma unroll
      for (int j = 0; j < 4; j++)
        acc[i][j] = __builtin_amdgcn_mfma_f32_16x16x32_bf16(af[i], bg[j], acc[i][j], 0, 0, 0);
    __syncthreads();
  }

  const int rq = (lane >> 4) * 4;
#pragma unroll
  for (int i = 0; i < 4; i++) {
#pragma unroll
    for (int r = 0; r < 4; r++) {
      const int slot = rt * BM + wr + i * 16 + rq + r;
      if (slot < ce) {
        const int g = base + slot;
        const int t = ltok[g];
        const float w = lw[g];
        float* orow = out + (size_t)t * HDIM + n0 + wc;
#pragma unroll
        for (int j = 0; j < 4; j++)
          atomicAdd(&orow[j * 16 + fr], w * acc[i][j][r]);
      }
    }
  }
}

extern "C" void kernel_launch(void* const* d_in, const int* in_sizes, int n_in,
                              void* d_out, int out_size, void* d_ws, size_t ws_size,
                              hipStream_t stream) {
  const float* x = (const float*)d_in[0];
  const float* rw = (const float*)d_in[1];
  const float* w1 = (const float*)d_in[2];
  const float* w2 = (const float*)d_in[3];
  float* out = (float*)d_out;
  char* ws = (char*)d_ws;

  hipMemsetAsync(d_out, 0, (size_t)out_size * sizeof(float), stream);
  if (ws_size < (size_t)WS_NEEDED) return;  // diagnostic: zeros -> absmax == ref max

  cvt_kernel<<<1024, 256, 0, stream>>>(x, (unsigned short*)(ws + WS_XB), NTOK * HDIM / 8);
  cvt_kernel<<<1024, 256, 0, stream>>>(w1, (unsigned short*)(ws + WS_W1B), NEXP * IDIM * HDIM / 8);
  cvt_kernel<<<1024, 256, 0, stream>>>(w2, (unsigned short*)(ws + WS_W2B), NEXP * HDIM * IDIM / 8);
  router_kernel<<<NTOK / 64, 256, 0, stream>>>(x, rw, ws);
  finalize_kernel<<<1, 64, 0, stream>>>(ws);
  build_lists<<<NTOK / 256, 256, 0, stream>>>(ws);
  gemm1_kernel<<<dim3(IDIM / BN, NTOK / BM, NEXP), 256, 0, stream>>>(ws);
  gemm2_kernel<<<dim3(HDIM / BN, NTOK / BM, NEXP), 256, 0, stream>>>(ws, out);
}

// Round 2
// 345.561 us; speedup vs baseline: 1.1192x; 1.1192x over previous
//
#include <hip/hip_runtime.h>
#include <hip/hip_bf16.h>

#define NTOK 8192
#define HDIM 768
#define IDIM 2048
#define NEXP 8
#define BM 128
#define BN 128
#define BK 64
#define LIST_CAP 17408   // sum_e roundup(cnt[e],128) <= 2T + 8*128
#define MAXTILES 136     // sum_e ceil(cnt[e]/128) <= 16384/128 + 7, padded

// ---- ws layout (byte offsets) ----
#define WS_CNT    0u          // int[8]
#define WS_CNT2   32u         // int[8]
#define WS_OFFP   64u         // int[8]  (128-padded prefix)
#define WS_RUN    96u         // float[8]
#define WS_NTIL   128u        // int[1]
#define WS_TTAB   192u        // int[MAXTILES]
#define WS_IMP    1024u       // float[128*8] per-block importance partials
#define WS_CNTP   5120u       // int[128*8]   per-block count partials
#define WS_TOPKI  9216u       // int[NTOK*2]   (overlaid by WS_TG after build_lists)
#define WS_TOPKP  74752u      // float[NTOK*2]
#define WS_TG     9216u       // int2[NTOK] — overlays WS_TOPKI (same slots, same thread)
#define WS_LTOK   140288u     // int[LIST_CAP]
#define WS_LW     209920u     // float[LIST_CAP]
#define WS_XB     279552u     // ushort bf16 [NTOK*HDIM]
#define WS_W1B    12862464u   // ushort bf16 [NEXP*IDIM*HDIM]
#define WS_W2B    38028288u   // ushort bf16 [NEXP*HDIM*IDIM]
#define WS_H      63194112u   // ushort bf16 [LIST_CAP*IDIM]
#define WS_SEL    279552u     // ushort bf16 [LIST_CAP*HDIM] — reuses XB+W1B (dead after gemm1)
#define WS_NEEDED 134497280u  // <= round-1 verified floor 134504448

typedef __attribute__((ext_vector_type(8))) __bf16 bf16x8;
typedef __attribute__((ext_vector_type(4))) float f32x4;

__device__ __forceinline__ unsigned short f2bf(float f) {
  unsigned int u = __float_as_uint(f);
  u += 0x7FFFu + ((u >> 16) & 1u);   // RNE (inputs finite)
  return (unsigned short)(u >> 16);
}
__device__ __forceinline__ float bf2f(unsigned short u) {
  return __uint_as_float(((unsigned int)u) << 16);
}

__device__ __forceinline__ void gload_lds16(const void* g, void* l) {
  __builtin_amdgcn_global_load_lds(
      (const __attribute__((address_space(1))) void*)g,
      (__attribute__((address_space(3))) void*)l, 16, 0, 0);
}

// ---------------- fp32 -> bf16 conversion ----------------
__global__ void cvt_kernel(const float* __restrict__ src,
                           unsigned short* __restrict__ dst, int n8) {
  int stride = gridDim.x * blockDim.x;
  const float4* s4 = (const float4*)src;
  uint4* d4 = (uint4*)dst;
  for (int i = blockIdx.x * blockDim.x + threadIdx.x; i < n8; i += stride) {
    float4 a = s4[2 * i];
    float4 b = s4[2 * i + 1];
    uint4 o;
    o.x = (unsigned)f2bf(a.x) | ((unsigned)f2bf(a.y) << 16);
    o.y = (unsigned)f2bf(a.z) | ((unsigned)f2bf(a.w) << 16);
    o.z = (unsigned)f2bf(b.x) | ((unsigned)f2bf(b.y) << 16);
    o.w = (unsigned)f2bf(b.z) | ((unsigned)f2bf(b.w) << 16);
    d4[i] = o;
  }
}

// ---------------- router: logits, softmax, top-2, partials ----------------
__global__ __launch_bounds__(256) void router_kernel(
    const float* __restrict__ x, const float* __restrict__ rw,
    char* __restrict__ ws) {
  __shared__ float rws[NEXP * HDIM];  // 24KB
  __shared__ float lg[64][NEXP];
  const int tid = threadIdx.x;
  const int t0 = blockIdx.x * 64;
  for (int i = tid; i < NEXP * HDIM / 4; i += 256)
    ((float4*)rws)[i] = ((const float4*)rw)[i];
  __syncthreads();
  for (int p = tid; p < 512; p += 256) {
    const int m = p >> 3, e = p & 7;
    const float* xr = x + (size_t)(t0 + m) * HDIM;
    const float* wr = rws + e * HDIM;
    float acc = 0.f;
    for (int h = 0; h < HDIM; h += 4) {
      float4 xv = *(const float4*)(xr + h);
      acc += xv.x * wr[h] + xv.y * wr[h + 1] + xv.z * wr[h + 2] + xv.w * wr[h + 3];
    }
    lg[m][e] = acc;
  }
  __syncthreads();
  if (tid < 64) {  // one wave: softmax + top2 + deterministic partials
    const int m = tid;
    float pr[8], mx = -1e30f;
    for (int e = 0; e < 8; e++) { pr[e] = lg[m][e]; mx = fmaxf(mx, pr[e]); }
    float s = 0.f;
    for (int e = 0; e < 8; e++) { pr[e] = __expf(pr[e] - mx); s += pr[e]; }
    float inv = 1.f / s;
    for (int e = 0; e < 8; e++) pr[e] *= inv;
    int i0 = 0;
    for (int e = 1; e < 8; e++) if (pr[e] > pr[i0]) i0 = e;
    int i1 = (i0 == 0) ? 1 : 0;
    for (int e = 0; e < 8; e++) if (e != i0 && pr[e] > pr[i1]) i1 = e;
    const int t = t0 + m;
    ((int*)(ws + WS_TOPKI))[2 * t] = i0;
    ((int*)(ws + WS_TOPKI))[2 * t + 1] = i1;
    ((float*)(ws + WS_TOPKP))[2 * t] = pr[i0];
    ((float*)(ws + WS_TOPKP))[2 * t + 1] = pr[i1];
    float* ip = (float*)(ws + WS_IMP) + blockIdx.x * 8;
    int* cp = (int*)(ws + WS_CNTP) + blockIdx.x * 8;
    for (int e = 0; e < 8; e++) {
      float v = pr[e];
      for (int off = 32; off; off >>= 1) v += __shfl_down(v, off);
      unsigned long long b0 = __ballot(i0 == e);
      unsigned long long b1 = __ballot(i1 == e);
      if (tid == 0) { ip[e] = v; cp[e] = __popcll(b0) + __popcll(b1); }
    }
  }
}

// ---------------- finalize: running[], counts, padded prefix, tile table ----
__global__ void finalize_kernel(char* __restrict__ ws) {
  const int tid = threadIdx.x;
  if (tid < 8) {
    float s = 0.f; int c = 0;
    const float* ip = (const float*)(ws + WS_IMP);
    const int* cp = (const int*)(ws + WS_CNTP);
    for (int b = 0; b < 128; b++) { s += ip[b * 8 + tid]; c += cp[b * 8 + tid]; }
    float running = 1.0f;
    float blended = running + 0.1f * (s - running);
    ((float*)(ws + WS_RUN))[tid] = blended + 0.01f;
    ((int*)(ws + WS_CNT))[tid] = c;
    ((int*)(ws + WS_CNT2))[tid] = 0;
  }
  __syncthreads();
  if (tid == 0) {
    const int* cnt = (const int*)(ws + WS_CNT);
    int* offp = (int*)(ws + WS_OFFP);
    int* ttab = (int*)(ws + WS_TTAB);
    int o = 0, n = 0;
    for (int e = 0; e < 8; e++) {
      offp[e] = o;
      int tl = (cnt[e] + BM - 1) / BM;
      o += tl * BM;
      for (int r = 0; r < tl; r++) ttab[n++] = (e << 8) | r;
    }
    *((int*)(ws + WS_NTIL)) = n;
  }
}

// ---------------- build per-expert lists + combine weights + slot map ------
__global__ void build_lists(char* __restrict__ ws) {
  const int t = blockIdx.x * blockDim.x + threadIdx.x;
  if (t >= NTOK) return;
  const int* ti = (const int*)(ws + WS_TOPKI);
  const float* tp = (const float*)(ws + WS_TOPKP);
  const float* run = (const float*)(ws + WS_RUN);
  int* cnt2 = (int*)(ws + WS_CNT2);
  const int* offp = (const int*)(ws + WS_OFFP);
  int* ltok = (int*)(ws + WS_LTOK);
  float* lw = (float*)(ws + WS_LW);
  const int e0 = ti[2 * t], e1 = ti[2 * t + 1];
  const float b0 = tp[2 * t] / run[e0], b1 = tp[2 * t + 1] / run[e1];
  const float inv = 1.f / (b0 + b1);
  int s0 = atomicAdd(&cnt2[e0], 1);
  int g0 = offp[e0] + s0; ltok[g0] = t; lw[g0] = b0 * inv;
  int s1 = atomicAdd(&cnt2[e1], 1);
  int g1 = offp[e1] + s1; ltok[g1] = t; lw[g1] = b1 * inv;
  // overlay: WS_TG[t] occupies exactly ti[2t..2t+1] which this thread has read
  ((int2*)(ws + WS_TG))[t] = make_int2(g0, g1);
}

// ---------------- GEMM1: h = silu(x_gather @ w1_e^T), K=768 ----------------
__global__ __launch_bounds__(256) void gemm1_kernel(char* __restrict__ ws) {
  __shared__ unsigned short As[BM * BK];  // 16KB, layout [128][64], XOR-swizzled k-slots
  __shared__ unsigned short Bs[BN * BK];  // 16KB
  const int nt = *(const int*)(ws + WS_NTIL);
  if ((int)blockIdx.y >= nt) return;
  const int tile = ((const int*)(ws + WS_TTAB))[blockIdx.y];
  const int e = tile >> 8, rt = tile & 255;
  const int ce = ((const int*)(ws + WS_CNT))[e];
  const int base = ((const int*)(ws + WS_OFFP))[e];
  const int* __restrict__ ltok = (const int*)(ws + WS_LTOK);
  const unsigned short* __restrict__ xb = (const unsigned short*)(ws + WS_XB);
  const unsigned short* __restrict__ w1b =
      (const unsigned short*)(ws + WS_W1B) + (size_t)e * IDIM * HDIM;
  unsigned short* __restrict__ hb = (unsigned short*)(ws + WS_H);

  const int tid = threadIdx.x;
  const int lane = tid & 63, wave = tid >> 6;
  const int lr = tid >> 3;                               // staging row 0..31 (per chunk)
  const int ko_sw = ((tid & 7) ^ (lr & 7)) * 8;          // swizzled k-slot (source side)
  const int n0 = blockIdx.x * BN;

  const unsigned short* ga[4];
  const unsigned short* gb[4];
#pragma unroll
  for (int c = 0; c < 4; c++) {
    int s = rt * BM + c * 32 + lr; s = (s < ce) ? s : (ce - 1);
    ga[c] = xb + (size_t)ltok[base + s] * HDIM + ko_sw;
    gb[c] = w1b + (size_t)(n0 + c * 32 + lr) * HDIM + ko_sw;
  }

  f32x4 acc[4][4];
#pragma unroll
  for (int i = 0; i < 4; i++)
#pragma unroll
    for (int j = 0; j < 4; j++) acc[i][j] = (f32x4){0.f, 0.f, 0.f, 0.f};

  const int wr = (wave >> 1) * 64, wc = (wave & 1) * 64;
  const int fr = lane & 15, hi = lane >> 4;
  unsigned short* lA = As + wave * 512;
  unsigned short* lB = Bs + wave * 512;

  for (int kb = 0; kb < HDIM; kb += BK) {
#pragma unroll
    for (int c = 0; c < 4; c++) {
      gload_lds16(ga[c] + kb, lA + c * 2048);
      gload_lds16(gb[c] + kb, lB + c * 2048);
    }
    __syncthreads();  // drains vmcnt before barrier (compiler-inserted)
#pragma unroll
    for (int ks = 0; ks < 2; ks++) {
      bf16x8 af[4], bg[4];
      const int sl = ((ks * 4 + hi) ^ (fr & 7)) * 8;     // swizzled read slot
#pragma unroll
      for (int i = 0; i < 4; i++)
        af[i] = *(const bf16x8*)&As[(wr + i * 16 + fr) * BK + sl];
#pragma unroll
      for (int j = 0; j < 4; j++)
        bg[j] = *(const bf16x8*)&Bs[(wc + j * 16 + fr) * BK + sl];
#pragma unroll
      for (int i = 0; i < 4; i++)
#pragma unroll
        for (int j = 0; j < 4; j++)
          acc[i][j] = __builtin_amdgcn_mfma_f32_16x16x32_bf16(af[i], bg[j], acc[i][j], 0, 0, 0);
    }
    __syncthreads();
  }

  const int rq = (lane >> 4) * 4;
#pragma unroll
  for (int i = 0; i < 4; i++) {
#pragma unroll
    for (int r = 0; r < 4; r++) {
      const int slot = rt * BM + wr + i * 16 + rq + r;
      unsigned short* hrow = hb + (size_t)(base + slot) * IDIM + n0 + wc;
#pragma unroll
      for (int j = 0; j < 4; j++) {
        float v = acc[i][j][r];
        float sv = v / (1.f + __expf(-v));
        hrow[j * 16 + fr] = f2bf(sv);
      }
    }
  }
}

// ---------------- GEMM2: sel[g] = lw[g] * (h @ w2_e^T) (bf16), K=2048 ------
__global__ __launch_bounds__(256) void gemm2_kernel(char* __restrict__ ws) {
  __shared__ unsigned short As[BM * BK];
  __shared__ unsigned short Bs[BN * BK];
  const int nt = *(const int*)(ws + WS_NTIL);
  if ((int)blockIdx.y >= nt) return;
  const int tile = ((const int*)(ws + WS_TTAB))[blockIdx.y];
  const int e = tile >> 8, rt = tile & 255;
  const int ce = ((const int*)(ws + WS_CNT))[e];
  const int base = ((const int*)(ws + WS_OFFP))[e];
  const float* __restrict__ lw = (const float*)(ws + WS_LW);
  const unsigned short* __restrict__ hb = (const unsigned short*)(ws + WS_H);
  const unsigned short* __restrict__ w2b =
      (const unsigned short*)(ws + WS_W2B) + (size_t)e * HDIM * IDIM;
  unsigned short* __restrict__ selb = (unsigned short*)(ws + WS_SEL);

  const int tid = threadIdx.x;
  const int lane = tid & 63, wave = tid >> 6;
  const int lr = tid >> 3;
  const int ko_sw = ((tid & 7) ^ (lr & 7)) * 8;
  const int n0 = blockIdx.x * BN;

  const unsigned short* ga[4];
  const unsigned short* gb[4];
#pragma unroll
  for (int c = 0; c < 4; c++) {
    ga[c] = hb + (size_t)(base + rt * BM + c * 32 + lr) * IDIM + ko_sw;  // padded rows defined
    gb[c] = w2b + (size_t)(n0 + c * 32 + lr) * IDIM + ko_sw;
  }

  f32x4 acc[4][4];
#pragma unroll
  for (int i = 0; i < 4; i++)
#pragma unroll
    for (int j = 0; j < 4; j++) acc[i][j] = (f32x4){0.f, 0.f, 0.f, 0.f};

  const int wr = (wave >> 1) * 64, wc = (wave & 1) * 64;
  const int fr = lane & 15, hi = lane >> 4;
  unsigned short* lA = As + wave * 512;
  unsigned short* lB = Bs + wave * 512;

  for (int kb = 0; kb < IDIM; kb += BK) {
#pragma unroll
    for (int c = 0; c < 4; c++) {
      gload_lds16(ga[c] + kb, lA + c * 2048);
      gload_lds16(gb[c] + kb, lB + c * 2048);
    }
    __syncthreads();
#pragma unroll
    for (int ks = 0; ks < 2; ks++) {
      bf16x8 af[4], bg[4];
      const int sl = ((ks * 4 + hi) ^ (fr & 7)) * 8;
#pragma unroll
      for (int i = 0; i < 4; i++)
        af[i] = *(const bf16x8*)&As[(wr + i * 16 + fr) * BK + sl];
#pragma unroll
      for (int j = 0; j < 4; j++)
        bg[j] = *(const bf16x8*)&Bs[(wc + j * 16 + fr) * BK + sl];
#pragma unroll
      for (int i = 0; i < 4; i++)
#pragma unroll
        for (int j = 0; j < 4; j++)
          acc[i][j] = __builtin_amdgcn_mfma_f32_16x16x32_bf16(af[i], bg[j], acc[i][j], 0, 0, 0);
    }
    __syncthreads();
  }

  const int rq = (lane >> 4) * 4;
#pragma unroll
  for (int i = 0; i < 4; i++) {
#pragma unroll
    for (int r = 0; r < 4; r++) {
      const int slot = rt * BM + wr + i * 16 + rq + r;
      if (slot < ce) {
        const int g = base + slot;
        const float w = lw[g];                      // weight pre-applied before bf16
        unsigned short* srow = selb + (size_t)g * HDIM + n0 + wc;
#pragma unroll
        for (int j = 0; j < 4; j++)
          srow[j * 16 + fr] = f2bf(w * acc[i][j][r]);
      }
    }
  }
}

// ---------------- combine: out[t] = sel[g0] + sel[g1] ----------------------
__global__ __launch_bounds__(192) void combine_kernel(const char* __restrict__ ws,
                                                      float* __restrict__ out) {
  const int t = blockIdx.x;
  const int c = threadIdx.x;                         // 192 threads: 4 floats each
  const int2 g = ((const int2*)(ws + WS_TG))[t];
  const unsigned short* selb = (const unsigned short*)(ws + WS_SEL);
  ushort4 a = *(const ushort4*)(selb + (size_t)g.x * HDIM + c * 4);
  ushort4 b = *(const ushort4*)(selb + (size_t)g.y * HDIM + c * 4);
  float4 o;
  o.x = bf2f(a.x) + bf2f(b.x);
  o.y = bf2f(a.y) + bf2f(b.y);
  o.z = bf2f(a.z) + bf2f(b.z);
  o.w = bf2f(a.w) + bf2f(b.w);
  ((float4*)out)[(size_t)t * (HDIM / 4) + c] = o;
}

extern "C" void kernel_launch(void* const* d_in, const int* in_sizes, int n_in,
                              void* d_out, int out_size, void* d_ws, size_t ws_size,
                              hipStream_t stream) {
  const float* x = (const float*)d_in[0];
  const float* rw = (const float*)d_in[1];
  const float* w1 = (const float*)d_in[2];
  const float* w2 = (const float*)d_in[3];
  float* out = (float*)d_out;
  char* ws = (char*)d_ws;

  if (ws_size < (size_t)WS_NEEDED) {  // diagnostic path: zeros
    hipMemsetAsync(d_out, 0, (size_t)out_size * sizeof(float), stream);
    return;
  }

  cvt_kernel<<<1024, 256, 0, stream>>>(x, (unsigned short*)(ws + WS_XB), NTOK * HDIM / 8);
  cvt_kernel<<<1024, 256, 0, stream>>>(w1, (unsigned short*)(ws + WS_W1B), NEXP * IDIM * HDIM / 8);
  cvt_kernel<<<1024, 256, 0, stream>>>(w2, (unsigned short*)(ws + WS_W2B), NEXP * HDIM * IDIM / 8);
  router_kernel<<<NTOK / 64, 256, 0, stream>>>(x, rw, ws);
  finalize_kernel<<<1, 64, 0, stream>>>(ws);
  build_lists<<<NTOK / 256, 256, 0, stream>>>(ws);
  gemm1_kernel<<<dim3(IDIM / BN, MAXTILES), 256, 0, stream>>>(ws);
  gemm2_kernel<<<dim3(HDIM / BN, MAXTILES), 256, 0, stream>>>(ws);
  combine_kernel<<<NTOK, 192, 0, stream>>>(ws, out);
}

// Round 3
// 261.236 us; speedup vs baseline: 1.4805x; 1.3228x over previous
//
#include <hip/hip_runtime.h>
#include <hip/hip_bf16.h>

#define NTOK 8192
#define HDIM 768
#define IDIM 2048
#define NEXP 8
#define BM 128
#define BN 128
#define BK 64
#define LIST_CAP 17408   // sum_e roundup(cnt[e],128) <= 2T + 8*128
#define MAXTILES 136     // sum_e ceil(cnt[e]/128) <= 16384/128 + 7, padded

// ---- ws layout (byte offsets) ----
#define WS_CNT    0u          // int[8]
#define WS_OFFP   64u         // int[8]  (128-padded prefix)
#define WS_RUN    96u         // float[8]
#define WS_NTIL   128u        // int[1]
#define WS_TTAB   192u        // int[MAXTILES]
#define WS_CNT2   768u        // int[8*16] — one counter per 64B cacheline
#define WS_IMP    1280u       // float[128*8] per-block importance partials
#define WS_CNTP   5376u       // int[128*8]   per-block count partials
#define WS_TOPKI  9472u       // int[NTOK*2]  (overlaid by WS_TG after build_lists)
#define WS_TOPKP  75008u      // float[NTOK*2]
#define WS_TG     9472u       // int2[NTOK] — overlays WS_TOPKI (same slots, same thread)
#define WS_LTOK   140544u     // int[LIST_CAP]
#define WS_LW     210176u     // float[LIST_CAP]
#define WS_XB     279808u     // ushort bf16 [NTOK*HDIM]
#define WS_W1B    12862720u   // ushort bf16 [NEXP*IDIM*HDIM]
#define WS_W2B    38028544u   // ushort bf16 [NEXP*HDIM*IDIM]
#define WS_H      63194368u   // ushort bf16 [LIST_CAP*IDIM]
#define WS_SEL    279808u     // ushort bf16 [LIST_CAP*HDIM] — reuses XB+W1B (dead after gemm1)
#define WS_NEEDED 134497536u  // <= round-1 verified floor 134504448

typedef __attribute__((ext_vector_type(8))) __bf16 bf16x8;
typedef __attribute__((ext_vector_type(4))) float f32x4;

__device__ __forceinline__ unsigned short f2bf(float f) {
  unsigned int u = __float_as_uint(f);
  u += 0x7FFFu + ((u >> 16) & 1u);   // RNE (inputs finite)
  return (unsigned short)(u >> 16);
}
__device__ __forceinline__ float bf2f(unsigned short u) {
  return __uint_as_float(((unsigned int)u) << 16);
}

__device__ __forceinline__ void gload_lds16(const void* g, void* l) {
  __builtin_amdgcn_global_load_lds(
      (const __attribute__((address_space(1))) void*)g,
      (__attribute__((address_space(3))) void*)l, 16, 0, 0);
}

// ---------------- fp32 -> bf16 conversion ----------------
__global__ void cvt_kernel(const float* __restrict__ src,
                           unsigned short* __restrict__ dst, int n8) {
  int stride = gridDim.x * blockDim.x;
  const float4* s4 = (const float4*)src;
  uint4* d4 = (uint4*)dst;
  for (int i = blockIdx.x * blockDim.x + threadIdx.x; i < n8; i += stride) {
    float4 a = s4[2 * i];
    float4 b = s4[2 * i + 1];
    uint4 o;
    o.x = (unsigned)f2bf(a.x) | ((unsigned)f2bf(a.y) << 16);
    o.y = (unsigned)f2bf(a.z) | ((unsigned)f2bf(a.w) << 16);
    o.z = (unsigned)f2bf(b.x) | ((unsigned)f2bf(b.y) << 16);
    o.w = (unsigned)f2bf(b.z) | ((unsigned)f2bf(b.w) << 16);
    d4[i] = o;
  }
}

// ---------------- router: logits, softmax, top-2, partials ----------------
__global__ __launch_bounds__(256) void router_kernel(
    const float* __restrict__ x, const float* __restrict__ rw,
    char* __restrict__ ws) {
  __shared__ float rws[NEXP * HDIM];  // 24KB
  __shared__ float lg[64][NEXP];
  const int tid = threadIdx.x;
  const int t0 = blockIdx.x * 64;
  for (int i = tid; i < NEXP * HDIM / 4; i += 256)
    ((float4*)rws)[i] = ((const float4*)rw)[i];
  __syncthreads();
  for (int p = tid; p < 512; p += 256) {
    const int m = p >> 3, e = p & 7;
    const float* xr = x + (size_t)(t0 + m) * HDIM;
    const float* wr = rws + e * HDIM;
    float acc = 0.f;
    for (int h = 0; h < HDIM; h += 4) {
      float4 xv = *(const float4*)(xr + h);
      acc += xv.x * wr[h] + xv.y * wr[h + 1] + xv.z * wr[h + 2] + xv.w * wr[h + 3];
    }
    lg[m][e] = acc;
  }
  __syncthreads();
  if (tid < 64) {  // one wave: softmax + top2 + deterministic partials
    const int m = tid;
    float pr[8], mx = -1e30f;
    for (int e = 0; e < 8; e++) { pr[e] = lg[m][e]; mx = fmaxf(mx, pr[e]); }
    float s = 0.f;
    for (int e = 0; e < 8; e++) { pr[e] = __expf(pr[e] - mx); s += pr[e]; }
    float inv = 1.f / s;
    for (int e = 0; e < 8; e++) pr[e] *= inv;
    int i0 = 0;
    for (int e = 1; e < 8; e++) if (pr[e] > pr[i0]) i0 = e;
    int i1 = (i0 == 0) ? 1 : 0;
    for (int e = 0; e < 8; e++) if (e != i0 && pr[e] > pr[i1]) i1 = e;
    const int t = t0 + m;
    ((int*)(ws + WS_TOPKI))[2 * t] = i0;
    ((int*)(ws + WS_TOPKI))[2 * t + 1] = i1;
    ((float*)(ws + WS_TOPKP))[2 * t] = pr[i0];
    ((float*)(ws + WS_TOPKP))[2 * t + 1] = pr[i1];
    float* ip = (float*)(ws + WS_IMP) + blockIdx.x * 8;
    int* cp = (int*)(ws + WS_CNTP) + blockIdx.x * 8;
    for (int e = 0; e < 8; e++) {
      float v = pr[e];
      for (int off = 32; off; off >>= 1) v += __shfl_down(v, off);
      unsigned long long b0 = __ballot(i0 == e);
      unsigned long long b1 = __ballot(i1 == e);
      if (tid == 0) { ip[e] = v; cp[e] = __popcll(b0) + __popcll(b1); }
    }
  }
}

// ---------------- finalize: running[], counts, padded prefix, tile table ----
__global__ void finalize_kernel(char* __restrict__ ws) {
  const int tid = threadIdx.x;
  if (tid < 8) {
    float s = 0.f; int c = 0;
    const float* ip = (const float*)(ws + WS_IMP);
    const int* cp = (const int*)(ws + WS_CNTP);
    for (int b = 0; b < 128; b++) { s += ip[b * 8 + tid]; c += cp[b * 8 + tid]; }
    float running = 1.0f;
    float blended = running + 0.1f * (s - running);
    ((float*)(ws + WS_RUN))[tid] = blended + 0.01f;
    ((int*)(ws + WS_CNT))[tid] = c;
    ((int*)(ws + WS_CNT2))[tid * 16] = 0;   // padded counters, 1 per cacheline
  }
  __syncthreads();
  if (tid == 0) {
    const int* cnt = (const int*)(ws + WS_CNT);
    int* offp = (int*)(ws + WS_OFFP);
    int* ttab = (int*)(ws + WS_TTAB);
    int o = 0, n = 0;
    for (int e = 0; e < 8; e++) {
      offp[e] = o;
      int tl = (cnt[e] + BM - 1) / BM;
      o += tl * BM;
      for (int r = 0; r < tl; r++) ttab[n++] = (e << 8) | r;
    }
    *((int*)(ws + WS_NTIL)) = n;
  }
}

// ------- build lists: wave-aggregated ballot ranks, 1 atomic/(wave,expert) --
__global__ __launch_bounds__(256) void build_lists(char* __restrict__ ws) {
  const int t = blockIdx.x * blockDim.x + threadIdx.x;
  const int lane = threadIdx.x & 63;
  const int* ti = (const int*)(ws + WS_TOPKI);
  const float* tp = (const float*)(ws + WS_TOPKP);
  const float* run = (const float*)(ws + WS_RUN);
  int* cnt2 = (int*)(ws + WS_CNT2);
  const int* offp = (const int*)(ws + WS_OFFP);
  int* ltok = (int*)(ws + WS_LTOK);
  float* lw = (float*)(ws + WS_LW);
  const int e0 = ti[2 * t], e1 = ti[2 * t + 1];
  const float b0 = tp[2 * t] / run[e0], b1 = tp[2 * t + 1] / run[e1];
  const float inv = 1.f / (b0 + b1);
  const unsigned long long lt = (1ull << lane) - 1ull;
  int g0 = 0, g1 = 0;
#pragma unroll
  for (int e = 0; e < 8; e++) {
    unsigned long long m0 = __ballot(e0 == e);
    unsigned long long m1 = __ballot(e1 == e);
    const int c0 = __popcll(m0);
    const int ctot = c0 + __popcll(m1);
    int base = 0;
    if (lane == 0 && ctot) base = atomicAdd(&cnt2[e * 16], ctot);
    base = __shfl(base, 0);
    if (e0 == e) g0 = offp[e] + base + __popcll(m0 & lt);
    if (e1 == e) g1 = offp[e] + base + c0 + __popcll(m1 & lt);
  }
  ltok[g0] = t; lw[g0] = b0 * inv;
  ltok[g1] = t; lw[g1] = b1 * inv;
  // overlay: WS_TG[t] occupies exactly ti[2t..2t+1] which this thread has read
  ((int2*)(ws + WS_TG))[t] = make_int2(g0, g1);
}

// ---------------- GEMM1: h = silu(x_gather @ w1_e^T), K=768 ----------------
__global__ __launch_bounds__(256) void gemm1_kernel(char* __restrict__ ws) {
  __shared__ unsigned short As[BM * BK];  // 16KB, layout [128][64], XOR-swizzled k-slots
  __shared__ unsigned short Bs[BN * BK];  // 16KB
  const int nt = *(const int*)(ws + WS_NTIL);
  if ((int)blockIdx.y >= nt) return;
  const int tile = ((const int*)(ws + WS_TTAB))[blockIdx.y];
  const int e = tile >> 8, rt = tile & 255;
  const int ce = ((const int*)(ws + WS_CNT))[e];
  const int base = ((const int*)(ws + WS_OFFP))[e];
  const int* __restrict__ ltok = (const int*)(ws + WS_LTOK);
  const unsigned short* __restrict__ xb = (const unsigned short*)(ws + WS_XB);
  const unsigned short* __restrict__ w1b =
      (const unsigned short*)(ws + WS_W1B) + (size_t)e * IDIM * HDIM;
  unsigned short* __restrict__ hb = (unsigned short*)(ws + WS_H);

  const int tid = threadIdx.x;
  const int lane = tid & 63, wave = tid >> 6;
  const int lr = tid >> 3;                               // staging row 0..31 (per chunk)
  const int ko_sw = ((tid & 7) ^ (lr & 7)) * 8;          // swizzled k-slot (source side)
  const int n0 = blockIdx.x * BN;

  const unsigned short* ga[4];
  const unsigned short* gb[4];
#pragma unroll
  for (int c = 0; c < 4; c++) {
    int s = rt * BM + c * 32 + lr; s = (s < ce) ? s : (ce - 1);
    ga[c] = xb + (size_t)ltok[base + s] * HDIM + ko_sw;
    gb[c] = w1b + (size_t)(n0 + c * 32 + lr) * HDIM + ko_sw;
  }

  f32x4 acc[4][4];
#pragma unroll
  for (int i = 0; i < 4; i++)
#pragma unroll
    for (int j = 0; j < 4; j++) acc[i][j] = (f32x4){0.f, 0.f, 0.f, 0.f};

  const int wr = (wave >> 1) * 64, wc = (wave & 1) * 64;
  const int fr = lane & 15, hi = lane >> 4;
  unsigned short* lA = As + wave * 512;
  unsigned short* lB = Bs + wave * 512;

  for (int kb = 0; kb < HDIM; kb += BK) {
#pragma unroll
    for (int c = 0; c < 4; c++) {
      gload_lds16(ga[c] + kb, lA + c * 2048);
      gload_lds16(gb[c] + kb, lB + c * 2048);
    }
    __syncthreads();  // drains vmcnt before barrier (compiler-inserted)
#pragma unroll
    for (int ks = 0; ks < 2; ks++) {
      bf16x8 af[4], bg[4];
      const int sl = ((ks * 4 + hi) ^ (fr & 7)) * 8;     // swizzled read slot
#pragma unroll
      for (int i = 0; i < 4; i++)
        af[i] = *(const bf16x8*)&As[(wr + i * 16 + fr) * BK + sl];
#pragma unroll
      for (int j = 0; j < 4; j++)
        bg[j] = *(const bf16x8*)&Bs[(wc + j * 16 + fr) * BK + sl];
#pragma unroll
      for (int i = 0; i < 4; i++)
#pragma unroll
        for (int j = 0; j < 4; j++)
          acc[i][j] = __builtin_amdgcn_mfma_f32_16x16x32_bf16(af[i], bg[j], acc[i][j], 0, 0, 0);
    }
    __syncthreads();
  }

  const int rq = (lane >> 4) * 4;
#pragma unroll
  for (int i = 0; i < 4; i++) {
#pragma unroll
    for (int r = 0; r < 4; r++) {
      const int slot = rt * BM + wr + i * 16 + rq + r;
      unsigned short* hrow = hb + (size_t)(base + slot) * IDIM + n0 + wc;
#pragma unroll
      for (int j = 0; j < 4; j++) {
        float v = acc[i][j][r];
        float sv = v / (1.f + __expf(-v));
        hrow[j * 16 + fr] = f2bf(sv);
      }
    }
  }
}

// ---------------- GEMM2: sel[g] = lw[g] * (h @ w2_e^T) (bf16), K=2048 ------
__global__ __launch_bounds__(256) void gemm2_kernel(char* __restrict__ ws) {
  __shared__ unsigned short As[BM * BK];
  __shared__ unsigned short Bs[BN * BK];
  const int nt = *(const int*)(ws + WS_NTIL);
  if ((int)blockIdx.y >= nt) return;
  const int tile = ((const int*)(ws + WS_TTAB))[blockIdx.y];
  const int e = tile >> 8, rt = tile & 255;
  const int ce = ((const int*)(ws + WS_CNT))[e];
  const int base = ((const int*)(ws + WS_OFFP))[e];
  const float* __restrict__ lw = (const float*)(ws + WS_LW);
  const unsigned short* __restrict__ hb = (const unsigned short*)(ws + WS_H);
  const unsigned short* __restrict__ w2b =
      (const unsigned short*)(ws + WS_W2B) + (size_t)e * HDIM * IDIM;
  unsigned short* __restrict__ selb = (unsigned short*)(ws + WS_SEL);

  const int tid = threadIdx.x;
  const int lane = tid & 63, wave = tid >> 6;
  const int lr = tid >> 3;
  const int ko_sw = ((tid & 7) ^ (lr & 7)) * 8;
  const int n0 = blockIdx.x * BN;

  const unsigned short* ga[4];
  const unsigned short* gb[4];
#pragma unroll
  for (int c = 0; c < 4; c++) {
    ga[c] = hb + (size_t)(base + rt * BM + c * 32 + lr) * IDIM + ko_sw;  // padded rows defined
    gb[c] = w2b + (size_t)(n0 + c * 32 + lr) * IDIM + ko_sw;
  }

  f32x4 acc[4][4];
#pragma unroll
  for (int i = 0; i < 4; i++)
#pragma unroll
    for (int j = 0; j < 4; j++) acc[i][j] = (f32x4){0.f, 0.f, 0.f, 0.f};

  const int wr = (wave >> 1) * 64, wc = (wave & 1) * 64;
  const int fr = lane & 15, hi = lane >> 4;
  unsigned short* lA = As + wave * 512;
  unsigned short* lB = Bs + wave * 512;

  for (int kb = 0; kb < IDIM; kb += BK) {
#pragma unroll
    for (int c = 0; c < 4; c++) {
      gload_lds16(ga[c] + kb, lA + c * 2048);
      gload_lds16(gb[c] + kb, lB + c * 2048);
    }
    __syncthreads();
#pragma unroll
    for (int ks = 0; ks < 2; ks++) {
      bf16x8 af[4], bg[4];
      const int sl = ((ks * 4 + hi) ^ (fr & 7)) * 8;
#pragma unroll
      for (int i = 0; i < 4; i++)
        af[i] = *(const bf16x8*)&As[(wr + i * 16 + fr) * BK + sl];
#pragma unroll
      for (int j = 0; j < 4; j++)
        bg[j] = *(const bf16x8*)&Bs[(wc + j * 16 + fr) * BK + sl];
#pragma unroll
      for (int i = 0; i < 4; i++)
#pragma unroll
        for (int j = 0; j < 4; j++)
          acc[i][j] = __builtin_amdgcn_mfma_f32_16x16x32_bf16(af[i], bg[j], acc[i][j], 0, 0, 0);
    }
    __syncthreads();
  }

  const int rq = (lane >> 4) * 4;
#pragma unroll
  for (int i = 0; i < 4; i++) {
#pragma unroll
    for (int r = 0; r < 4; r++) {
      const int slot = rt * BM + wr + i * 16 + rq + r;
      if (slot < ce) {
        const int g = base + slot;
        const float w = lw[g];                      // weight pre-applied before bf16
        unsigned short* srow = selb + (size_t)g * HDIM + n0 + wc;
#pragma unroll
        for (int j = 0; j < 4; j++)
          srow[j * 16 + fr] = f2bf(w * acc[i][j][r]);
      }
    }
  }
}

// ---------------- combine: out[t] = sel[g0] + sel[g1] ----------------------
__global__ __launch_bounds__(192) void combine_kernel(const char* __restrict__ ws,
                                                      float* __restrict__ out) {
  const int t = blockIdx.x;
  const int c = threadIdx.x;                         // 192 threads: 4 floats each
  const int2 g = ((const int2*)(ws + WS_TG))[t];
  const unsigned short* selb = (const unsigned short*)(ws + WS_SEL);
  ushort4 a = *(const ushort4*)(selb + (size_t)g.x * HDIM + c * 4);
  ushort4 b = *(const ushort4*)(selb + (size_t)g.y * HDIM + c * 4);
  float4 o;
  o.x = bf2f(a.x) + bf2f(b.x);
  o.y = bf2f(a.y) + bf2f(b.y);
  o.z = bf2f(a.z) + bf2f(b.z);
  o.w = bf2f(a.w) + bf2f(b.w);
  ((float4*)out)[(size_t)t * (HDIM / 4) + c] = o;
}

extern "C" void kernel_launch(void* const* d_in, const int* in_sizes, int n_in,
                              void* d_out, int out_size, void* d_ws, size_t ws_size,
                              hipStream_t stream) {
  const float* x = (const float*)d_in[0];
  const float* rw = (const float*)d_in[1];
  const float* w1 = (const float*)d_in[2];
  const float* w2 = (const float*)d_in[3];
  float* out = (float*)d_out;
  char* ws = (char*)d_ws;

  if (ws_size < (size_t)WS_NEEDED) {  // diagnostic path: zeros
    hipMemsetAsync(d_out, 0, (size_t)out_size * sizeof(float), stream);
    return;
  }

  cvt_kernel<<<1024, 256, 0, stream>>>(x, (unsigned short*)(ws + WS_XB), NTOK * HDIM / 8);
  cvt_kernel<<<1024, 256, 0, stream>>>(w1, (unsigned short*)(ws + WS_W1B), NEXP * IDIM * HDIM / 8);
  cvt_kernel<<<1024, 256, 0, stream>>>(w2, (unsigned short*)(ws + WS_W2B), NEXP * HDIM * IDIM / 8);
  router_kernel<<<NTOK / 64, 256, 0, stream>>>(x, rw, ws);
  finalize_kernel<<<1, 64, 0, stream>>>(ws);
  build_lists<<<NTOK / 256, 256, 0, stream>>>(ws);
  gemm1_kernel<<<dim3(IDIM / BN, MAXTILES), 256, 0, stream>>>(ws);
  gemm2_kernel<<<dim3(HDIM / BN, MAXTILES), 256, 0, stream>>>(ws);
  combine_kernel<<<NTOK, 192, 0, stream>>>(ws, out);
}

// Round 4
// 244.758 us; speedup vs baseline: 1.5802x; 1.0673x over previous
//
#include <hip/hip_runtime.h>
#include <hip/hip_bf16.h>

#define NTOK 8192
#define HDIM 768
#define IDIM 2048
#define NEXP 8
#define BM 128
#define BN 128
#define BK 64
#define LIST_CAP 17408   // sum_e roundup(cnt[e],128) <= 2T + 8*128
#define MAXTILES 136     // sum_e ceil(cnt[e]/128) <= 128 + 8

// ---- ws layout (byte offsets) ----
#define WS_CNT    0u          // int[8]
#define WS_OFFP   64u         // int[8]  (128-padded prefix)
#define WS_RUN    96u         // float[8]
#define WS_NTIL   128u        // int[1]
#define WS_TTAB   192u        // int[MAXTILES]
#define WS_CNT2   768u        // int[8*16] — one counter per 64B cacheline
#define WS_IMP    1280u       // float[256*8] per-block importance partials
#define WS_CNTP   9472u       // int[256*8]   per-block count partials
#define WS_TOPKI  17664u      // uchar2[NTOK]
#define WS_TOPKP  34048u      // float[NTOK*2] (overlaid by WS_TG after build_lists)
#define WS_TG     34048u      // int2[NTOK] — overlays TOPKP (same 8B, same thread)
#define WS_LTOK   99584u      // int[LIST_CAP]
#define WS_LW     169216u     // float[LIST_CAP]
#define WS_XB     238848u     // ushort bf16 [NTOK*HDIM]
#define WS_W1B    12821760u   // ushort bf16 [NEXP*IDIM*HDIM]
#define WS_W2B    37987584u   // ushort bf16 [NEXP*HDIM*IDIM]
#define WS_H      63153408u   // ushort bf16 [LIST_CAP*IDIM]
#define WS_SEL    238848u     // ushort bf16 [LIST_CAP*HDIM] — reuses XB+W1B (dead after gemm1)
#define WS_NEEDED 134456576u  // <= round-1 verified floor 134504448

typedef __attribute__((ext_vector_type(8))) __bf16 bf16x8;
typedef __attribute__((ext_vector_type(4))) float f32x4;

__device__ __forceinline__ unsigned short f2bf(float f) {
  unsigned int u = __float_as_uint(f);
  u += 0x7FFFu + ((u >> 16) & 1u);   // RNE (inputs finite)
  return (unsigned short)(u >> 16);
}
__device__ __forceinline__ float bf2f(unsigned short u) {
  return __uint_as_float(((unsigned int)u) << 16);
}

__device__ __forceinline__ void gload_lds16(const void* g, void* l) {
  __builtin_amdgcn_global_load_lds(
      (const __attribute__((address_space(1))) void*)g,
      (__attribute__((address_space(3))) void*)l, 16, 0, 0);
}

// ---------------- fp32 -> bf16 conversion ----------------
__global__ void cvt_kernel(const float* __restrict__ src,
                           unsigned short* __restrict__ dst, int n8) {
  int stride = gridDim.x * blockDim.x;
  const float4* s4 = (const float4*)src;
  uint4* d4 = (uint4*)dst;
  for (int i = blockIdx.x * blockDim.x + threadIdx.x; i < n8; i += stride) {
    float4 a = s4[2 * i];
    float4 b = s4[2 * i + 1];
    uint4 o;
    o.x = (unsigned)f2bf(a.x) | ((unsigned)f2bf(a.y) << 16);
    o.y = (unsigned)f2bf(a.z) | ((unsigned)f2bf(a.w) << 16);
    o.z = (unsigned)f2bf(b.x) | ((unsigned)f2bf(b.y) << 16);
    o.w = (unsigned)f2bf(b.z) | ((unsigned)f2bf(b.w) << 16);
    d4[i] = o;
  }
}

// ------------- router: 32 tokens/block, 256 blocks -------------
__global__ __launch_bounds__(256) void router_kernel(
    const float* __restrict__ x, const float* __restrict__ rw,
    char* __restrict__ ws) {
  __shared__ float rws[NEXP * HDIM];  // 24KB
  __shared__ float lg[32][NEXP];
  const int tid = threadIdx.x;
  const int t0 = blockIdx.x * 32;
  for (int i = tid; i < NEXP * HDIM / 4; i += 256)
    ((float4*)rws)[i] = ((const float4*)rw)[i];
  __syncthreads();
  {  // 256 (token,expert) dots, 1 per thread
    const int m = tid >> 3, e = tid & 7;
    const float* xr = x + (size_t)(t0 + m) * HDIM;
    const float* wr = rws + e * HDIM;
    float acc = 0.f;
    for (int h = 0; h < HDIM; h += 4) {
      float4 xv = *(const float4*)(xr + h);
      acc += xv.x * wr[h] + xv.y * wr[h + 1] + xv.z * wr[h + 2] + xv.w * wr[h + 3];
    }
    lg[m][e] = acc;
  }
  __syncthreads();
  if (tid < 32) {  // lanes 0..31 of wave 0: softmax + top2 + partials
    const int m = tid;
    float pr[8], mx = -1e30f;
    for (int e = 0; e < 8; e++) { pr[e] = lg[m][e]; mx = fmaxf(mx, pr[e]); }
    float s = 0.f;
    for (int e = 0; e < 8; e++) { pr[e] = __expf(pr[e] - mx); s += pr[e]; }
    float inv = 1.f / s;
    for (int e = 0; e < 8; e++) pr[e] *= inv;
    int i0 = 0;
    for (int e = 1; e < 8; e++) if (pr[e] > pr[i0]) i0 = e;
    int i1 = (i0 == 0) ? 1 : 0;
    for (int e = 0; e < 8; e++) if (e != i0 && pr[e] > pr[i1]) i1 = e;
    const int t = t0 + m;
    ((uchar2*)(ws + WS_TOPKI))[t] = make_uchar2((unsigned char)i0, (unsigned char)i1);
    ((float*)(ws + WS_TOPKP))[2 * t] = pr[i0];
    ((float*)(ws + WS_TOPKP))[2 * t + 1] = pr[i1];
    float* ip = (float*)(ws + WS_IMP) + blockIdx.x * 8;
    int* cp = (int*)(ws + WS_CNTP) + blockIdx.x * 8;
    for (int e = 0; e < 8; e++) {
      float v = pr[e];
      for (int off = 16; off; off >>= 1) v += __shfl_down(v, off);  // lanes 0..31 only
      unsigned long long b0 = __ballot(i0 == e);   // high 32 bits are 0 (inactive)
      unsigned long long b1 = __ballot(i1 == e);
      if (tid == 0) { ip[e] = v; cp[e] = __popcll(b0) + __popcll(b1); }
    }
  }
}

// ---------------- finalize: running[], counts, padded prefix, tile table ----
__global__ void finalize_kernel(char* __restrict__ ws) {
  const int tid = threadIdx.x;
  if (tid < 8) {
    float s = 0.f; int c = 0;
    const float* ip = (const float*)(ws + WS_IMP);
    const int* cp = (const int*)(ws + WS_CNTP);
    for (int b = 0; b < 256; b++) { s += ip[b * 8 + tid]; c += cp[b * 8 + tid]; }
    float running = 1.0f;
    float blended = running + 0.1f * (s - running);
    ((float*)(ws + WS_RUN))[tid] = blended + 0.01f;
    ((int*)(ws + WS_CNT))[tid] = c;
    ((int*)(ws + WS_CNT2))[tid * 16] = 0;   // padded counters, 1 per cacheline
  }
  __syncthreads();
  if (tid == 0) {
    const int* cnt = (const int*)(ws + WS_CNT);
    int* offp = (int*)(ws + WS_OFFP);
    int* ttab = (int*)(ws + WS_TTAB);
    int o = 0, n = 0;
    for (int e = 0; e < 8; e++) {
      offp[e] = o;
      int tl = (cnt[e] + BM - 1) / BM;
      o += tl * BM;
      for (int r = 0; r < tl; r++) ttab[n++] = (e << 8) | r;
    }
    *((int*)(ws + WS_NTIL)) = n;
  }
}

// ------- build lists: wave-aggregated ballot ranks, 1 atomic/(wave,expert) --
__global__ __launch_bounds__(256) void build_lists(char* __restrict__ ws) {
  const int t = blockIdx.x * blockDim.x + threadIdx.x;
  const int lane = threadIdx.x & 63;
  const uchar2* ti = (const uchar2*)(ws + WS_TOPKI);
  const float* tp = (const float*)(ws + WS_TOPKP);
  const float* run = (const float*)(ws + WS_RUN);
  int* cnt2 = (int*)(ws + WS_CNT2);
  const int* offp = (const int*)(ws + WS_OFFP);
  int* ltok = (int*)(ws + WS_LTOK);
  float* lw = (float*)(ws + WS_LW);
  const uchar2 ee = ti[t];
  const int e0 = ee.x, e1 = ee.y;
  const float b0 = tp[2 * t] / run[e0], b1 = tp[2 * t + 1] / run[e1];
  const float inv = 1.f / (b0 + b1);
  const unsigned long long lt = (1ull << lane) - 1ull;
  int g0 = 0, g1 = 0;
#pragma unroll
  for (int e = 0; e < 8; e++) {
    unsigned long long m0 = __ballot(e0 == e);
    unsigned long long m1 = __ballot(e1 == e);
    const int c0 = __popcll(m0);
    const int ctot = c0 + __popcll(m1);
    int base = 0;
    if (lane == 0 && ctot) base = atomicAdd(&cnt2[e * 16], ctot);
    base = __shfl(base, 0);
    if (e0 == e) g0 = offp[e] + base + __popcll(m0 & lt);
    if (e1 == e) g1 = offp[e] + base + c0 + __popcll(m1 & lt);
  }
  ltok[g0] = t; lw[g0] = b0 * inv;
  ltok[g1] = t; lw[g1] = b1 * inv;
  // overlay: WS_TG[t] occupies exactly tp[2t..2t+1] which this thread has read
  ((int2*)(ws + WS_TG))[t] = make_int2(g0, g1);
}

// ======== pipelined GEMM core (shared pattern, counted vmcnt) ========
// Per iteration: ds_read frags(buf cur) -> lgkm0+bar -> STAGE(cur,t+2)
//                -> MFMA -> vmcnt(8)/vmcnt(0 tail) -> bar -> flip.
#define GEMM_PIPELINE(NK)                                                      \
  {                                                                            \
    /* prologue: stage tiles 0 and 1 */                                        \
    stage(0, 0);                                                               \
    stage(1, 1);                                                               \
    asm volatile("s_waitcnt vmcnt(8)" ::: "memory");                           \
    __builtin_amdgcn_sched_barrier(0);                                         \
    asm volatile("s_barrier" ::: "memory");                                    \
    int cur = 0;                                                               \
    for (int t = 0; t < (NK); ++t) {                                           \
      bf16x8 af[2][4], bg[2][4];                                               \
      const unsigned short* rA = &SB[cur][0][0];                               \
      const unsigned short* rB = &SB[cur][1][0];                               \
      _Pragma("unroll") for (int ks = 0; ks < 2; ks++) {                       \
        const int sl = ((ks * 4 + hi) ^ (fr & 7)) * 8;                         \
        _Pragma("unroll") for (int i = 0; i < 4; i++)                          \
            af[ks][i] = *(const bf16x8*)&rA[(wr + i * 16 + fr) * BK + sl];     \
        _Pragma("unroll") for (int j = 0; j < 4; j++)                          \
            bg[ks][j] = *(const bf16x8*)&rB[(wc + j * 16 + fr) * BK + sl];     \
      }                                                                        \
      asm volatile("s_waitcnt lgkmcnt(0)" ::: "memory"); /* my reads done */   \
      __builtin_amdgcn_sched_barrier(0);                                       \
      asm volatile("s_barrier" ::: "memory");            /* all reads done */  \
      if (t + 2 < (NK)) stage(cur, t + 2);                                     \
      __builtin_amdgcn_s_setprio(1);                                           \
      _Pragma("unroll") for (int ks = 0; ks < 2; ks++)                         \
          _Pragma("unroll") for (int i = 0; i < 4; i++)                        \
              _Pragma("unroll") for (int j = 0; j < 4; j++)                    \
                  acc[i][j] = __builtin_amdgcn_mfma_f32_16x16x32_bf16(         \
                      af[ks][i], bg[ks][j], acc[i][j], 0, 0, 0);               \
      __builtin_amdgcn_s_setprio(0);                                           \
      if (t + 2 < (NK)) {                                                      \
        asm volatile("s_waitcnt vmcnt(8)" ::: "memory"); /* t+1 landed */      \
      } else {                                                                 \
        asm volatile("s_waitcnt vmcnt(0)" ::: "memory"); /* tail drain */      \
      }                                                                        \
      __builtin_amdgcn_sched_barrier(0);                                       \
      asm volatile("s_barrier" ::: "memory");            /* t+1 ready */       \
      cur ^= 1;                                                                \
    }                                                                          \
  }

// ---------------- GEMM1: h = silu(x_gather @ w1_e^T), K=768 ----------------
__global__ __launch_bounds__(256) void gemm1_kernel(char* __restrict__ ws) {
  __shared__ unsigned short SB[2][2][BM * BK];  // 64KB: [dbuf][A/B][128][64]
  const int nt = *(const int*)(ws + WS_NTIL);
  if ((int)blockIdx.y >= nt) return;
  const int tile = ((const int*)(ws + WS_TTAB))[blockIdx.y];
  const int e = tile >> 8, rt = tile & 255;
  const int ce = ((const int*)(ws + WS_CNT))[e];
  const int base = ((const int*)(ws + WS_OFFP))[e];
  const int* __restrict__ ltok = (const int*)(ws + WS_LTOK);
  const unsigned short* __restrict__ xb = (const unsigned short*)(ws + WS_XB);
  const unsigned short* __restrict__ w1b =
      (const unsigned short*)(ws + WS_W1B) + (size_t)e * IDIM * HDIM;
  unsigned short* __restrict__ hb = (unsigned short*)(ws + WS_H);

  const int tid = threadIdx.x;
  const int lane = tid & 63, wave = tid >> 6;
  const int lr = tid >> 3;                               // staging row 0..31 (per chunk)
  const int ko_sw = ((tid & 7) ^ (lr & 7)) * 8;          // swizzled k-slot (source side)
  const int n0 = blockIdx.x * BN;

  const unsigned short* ga[4];
  const unsigned short* gb[4];
#pragma unroll
  for (int c = 0; c < 4; c++) {
    int s = rt * BM + c * 32 + lr; s = (s < ce) ? s : (ce - 1);
    ga[c] = xb + (size_t)ltok[base + s] * HDIM + ko_sw;
    gb[c] = w1b + (size_t)(n0 + c * 32 + lr) * HDIM + ko_sw;
  }

  auto stage = [&](int buf, int kt) {
    unsigned short* dA = &SB[buf][0][wave * 512];
    unsigned short* dB = &SB[buf][1][wave * 512];
#pragma unroll
    for (int c = 0; c < 4; c++) {
      gload_lds16(ga[c] + kt * BK, dA + c * 2048);
      gload_lds16(gb[c] + kt * BK, dB + c * 2048);
    }
  };

  f32x4 acc[4][4];
#pragma unroll
  for (int i = 0; i < 4; i++)
#pragma unroll
    for (int j = 0; j < 4; j++) acc[i][j] = (f32x4){0.f, 0.f, 0.f, 0.f};

  const int wr = (wave >> 1) * 64, wc = (wave & 1) * 64;
  const int fr = lane & 15, hi = lane >> 4;

  GEMM_PIPELINE(HDIM / BK)

  const int rq = (lane >> 4) * 4;
#pragma unroll
  for (int i = 0; i < 4; i++) {
#pragma unroll
    for (int r = 0; r < 4; r++) {
      const int slot = rt * BM + wr + i * 16 + rq + r;
      unsigned short* hrow = hb + (size_t)(base + slot) * IDIM + n0 + wc;
#pragma unroll
      for (int j = 0; j < 4; j++) {
        float v = acc[i][j][r];
        float sv = v / (1.f + __expf(-v));
        hrow[j * 16 + fr] = f2bf(sv);
      }
    }
  }
}

// ---------------- GEMM2: sel[g] = lw[g] * (h @ w2_e^T) (bf16), K=2048 ------
__global__ __launch_bounds__(256) void gemm2_kernel(char* __restrict__ ws) {
  __shared__ unsigned short SB[2][2][BM * BK];  // 64KB
  const int nt = *(const int*)(ws + WS_NTIL);
  if ((int)blockIdx.y >= nt) return;
  const int tile = ((const int*)(ws + WS_TTAB))[blockIdx.y];
  const int e = tile >> 8, rt = tile & 255;
  const int ce = ((const int*)(ws + WS_CNT))[e];
  const int base = ((const int*)(ws + WS_OFFP))[e];
  const float* __restrict__ lw = (const float*)(ws + WS_LW);
  const unsigned short* __restrict__ hb = (const unsigned short*)(ws + WS_H);
  const unsigned short* __restrict__ w2b =
      (const unsigned short*)(ws + WS_W2B) + (size_t)e * HDIM * IDIM;
  unsigned short* __restrict__ selb = (unsigned short*)(ws + WS_SEL);

  const int tid = threadIdx.x;
  const int lane = tid & 63, wave = tid >> 6;
  const int lr = tid >> 3;
  const int ko_sw = ((tid & 7) ^ (lr & 7)) * 8;
  const int n0 = blockIdx.x * BN;

  const unsigned short* ga[4];
  const unsigned short* gb[4];
#pragma unroll
  for (int c = 0; c < 4; c++) {
    ga[c] = hb + (size_t)(base + rt * BM + c * 32 + lr) * IDIM + ko_sw;  // pad rows defined
    gb[c] = w2b + (size_t)(n0 + c * 32 + lr) * IDIM + ko_sw;
  }

  auto stage = [&](int buf, int kt) {
    unsigned short* dA = &SB[buf][0][wave * 512];
    unsigned short* dB = &SB[buf][1][wave * 512];
#pragma unroll
    for (int c = 0; c < 4; c++) {
      gload_lds16(ga[c] + kt * BK, dA + c * 2048);
      gload_lds16(gb[c] + kt * BK, dB + c * 2048);
    }
  };

  f32x4 acc[4][4];
#pragma unroll
  for (int i = 0; i < 4; i++)
#pragma unroll
    for (int j = 0; j < 4; j++) acc[i][j] = (f32x4){0.f, 0.f, 0.f, 0.f};

  const int wr = (wave >> 1) * 64, wc = (wave & 1) * 64;
  const int fr = lane & 15, hi = lane >> 4;

  GEMM_PIPELINE(IDIM / BK)

  const int rq = (lane >> 4) * 4;
#pragma unroll
  for (int i = 0; i < 4; i++) {
#pragma unroll
    for (int r = 0; r < 4; r++) {
      const int slot = rt * BM + wr + i * 16 + rq + r;
      if (slot < ce) {
        const int g = base + slot;
        const float w = lw[g];                      // weight pre-applied before bf16
        unsigned short* srow = selb + (size_t)g * HDIM + n0 + wc;
#pragma unroll
        for (int j = 0; j < 4; j++)
          srow[j * 16 + fr] = f2bf(w * acc[i][j][r]);
      }
    }
  }
}

// ---------------- combine: out[t] = sel[g0] + sel[g1] ----------------------
__global__ __launch_bounds__(192) void combine_kernel(const char* __restrict__ ws,
                                                      float* __restrict__ out) {
  const int t = blockIdx.x;
  const int c = threadIdx.x;                         // 192 threads: 4 floats each
  const int2 g = ((const int2*)(ws + WS_TG))[t];
  const unsigned short* selb = (const unsigned short*)(ws + WS_SEL);
  ushort4 a = *(const ushort4*)(selb + (size_t)g.x * HDIM + c * 4);
  ushort4 b = *(const ushort4*)(selb + (size_t)g.y * HDIM + c * 4);
  float4 o;
  o.x = bf2f(a.x) + bf2f(b.x);
  o.y = bf2f(a.y) + bf2f(b.y);
  o.z = bf2f(a.z) + bf2f(b.z);
  o.w = bf2f(a.w) + bf2f(b.w);
  ((float4*)out)[(size_t)t * (HDIM / 4) + c] = o;
}

extern "C" void kernel_launch(void* const* d_in, const int* in_sizes, int n_in,
                              void* d_out, int out_size, void* d_ws, size_t ws_size,
                              hipStream_t stream) {
  const float* x = (const float*)d_in[0];
  const float* rw = (const float*)d_in[1];
  const float* w1 = (const float*)d_in[2];
  const float* w2 = (const float*)d_in[3];
  float* out = (float*)d_out;
  char* ws = (char*)d_ws;

  if (ws_size < (size_t)WS_NEEDED) {  // diagnostic path: zeros
    hipMemsetAsync(d_out, 0, (size_t)out_size * sizeof(float), stream);
    return;
  }

  cvt_kernel<<<1024, 256, 0, stream>>>(x, (unsigned short*)(ws + WS_XB), NTOK * HDIM / 8);
  cvt_kernel<<<1024, 256, 0, stream>>>(w1, (unsigned short*)(ws + WS_W1B), NEXP * IDIM * HDIM / 8);
  cvt_kernel<<<1024, 256, 0, stream>>>(w2, (unsigned short*)(ws + WS_W2B), NEXP * HDIM * IDIM / 8);
  router_kernel<<<NTOK / 32, 256, 0, stream>>>(x, rw, ws);
  finalize_kernel<<<1, 64, 0, stream>>>(ws);
  build_lists<<<NTOK / 256, 256, 0, stream>>>(ws);
  gemm1_kernel<<<dim3(IDIM / BN, MAXTILES), 256, 0, stream>>>(ws);
  gemm2_kernel<<<dim3(HDIM / BN, MAXTILES), 256, 0, stream>>>(ws);
  combine_kernel<<<NTOK, 192, 0, stream>>>(ws, out);
}

// Round 5
// 212.112 us; speedup vs baseline: 1.8234x; 1.1539x over previous
//
#include <hip/hip_runtime.h>
#include <hip/hip_bf16.h>

#define NTOK 8192
#define HDIM 768
#define IDIM 2048
#define NEXP 8
#define BM 128
#define BN 128
#define BK 64
#define LIST_CAP 17408   // sum_e roundup(cnt[e],128) <= 2T + 8*128
#define MAXTILES 136     // sum_e ceil(cnt[e]/128) <= 128 + 8

// ---- ws layout (byte offsets) ----
#define WS_CNT    0u          // int[8]
#define WS_OFFP   64u         // int[8]  (128-padded prefix)
#define WS_RUN    96u         // float[8]
#define WS_NTIL   128u        // int[1]
#define WS_TTAB   192u        // int[MAXTILES]
#define WS_CNT2   768u        // int[8*16] — one counter per 64B cacheline
#define WS_IMP    1280u       // float[256*8] per-block importance partials
#define WS_CNTP   9472u       // int[256*8]   per-block count partials
#define WS_TOPKI  17664u      // uchar2[NTOK]
#define WS_TOPKP  34048u      // float[NTOK*2] (overlaid by WS_TG after build_lists)
#define WS_TG     34048u      // int2[NTOK] — overlays TOPKP (same 8B, same thread)
#define WS_LTOK   99584u      // int[LIST_CAP]
#define WS_LW     169216u     // float[LIST_CAP]
#define WS_XB     238848u     // ushort bf16 [NTOK*HDIM]
#define WS_W1B    12821760u   // ushort bf16 [NEXP*IDIM*HDIM]
#define WS_W2B    37987584u   // ushort bf16 [NEXP*HDIM*IDIM]
#define WS_H      63153408u   // ushort bf16 [LIST_CAP*IDIM]
#define WS_SEL    238848u     // ushort bf16 [LIST_CAP*HDIM] — reuses XB+W1B (dead after gemm1)
#define WS_NEEDED 134456576u  // <= round-1 verified floor 134504448

typedef __attribute__((ext_vector_type(8))) __bf16 bf16x8;
typedef __attribute__((ext_vector_type(4))) float f32x4;

__device__ __forceinline__ unsigned short f2bf(float f) {
  unsigned int u = __float_as_uint(f);
  u += 0x7FFFu + ((u >> 16) & 1u);   // RNE (inputs finite)
  return (unsigned short)(u >> 16);
}
__device__ __forceinline__ float bf2f(unsigned short u) {
  return __uint_as_float(((unsigned int)u) << 16);
}

__device__ __forceinline__ void gload_lds16(const void* g, void* l) {
  __builtin_amdgcn_global_load_lds(
      (const __attribute__((address_space(1))) void*)g,
      (__attribute__((address_space(3))) void*)l, 16, 0, 0);
}

// ---------------- fp32 -> bf16 conversion ----------------
__global__ void cvt_kernel(const float* __restrict__ src,
                           unsigned short* __restrict__ dst, int n8) {
  int stride = gridDim.x * blockDim.x;
  const float4* s4 = (const float4*)src;
  uint4* d4 = (uint4*)dst;
  for (int i = blockIdx.x * blockDim.x + threadIdx.x; i < n8; i += stride) {
    float4 a = s4[2 * i];
    float4 b = s4[2 * i + 1];
    uint4 o;
    o.x = (unsigned)f2bf(a.x) | ((unsigned)f2bf(a.y) << 16);
    o.y = (unsigned)f2bf(a.z) | ((unsigned)f2bf(a.w) << 16);
    o.z = (unsigned)f2bf(b.x) | ((unsigned)f2bf(b.y) << 16);
    o.w = (unsigned)f2bf(b.z) | ((unsigned)f2bf(b.w) << 16);
    d4[i] = o;
  }
}

// ------------- router: 32 tokens/block, 256 blocks -------------
__global__ __launch_bounds__(256) void router_kernel(
    const float* __restrict__ x, const float* __restrict__ rw,
    char* __restrict__ ws) {
  __shared__ float rws[NEXP * HDIM];  // 24KB
  __shared__ float lg[32][NEXP];
  const int tid = threadIdx.x;
  const int t0 = blockIdx.x * 32;
  for (int i = tid; i < NEXP * HDIM / 4; i += 256)
    ((float4*)rws)[i] = ((const float4*)rw)[i];
  __syncthreads();
  {  // 256 (token,expert) dots, 1 per thread
    const int m = tid >> 3, e = tid & 7;
    const float* xr = x + (size_t)(t0 + m) * HDIM;
    const float* wr = rws + e * HDIM;
    float acc = 0.f;
    for (int h = 0; h < HDIM; h += 4) {
      float4 xv = *(const float4*)(xr + h);
      acc += xv.x * wr[h] + xv.y * wr[h + 1] + xv.z * wr[h + 2] + xv.w * wr[h + 3];
    }
    lg[m][e] = acc;
  }
  __syncthreads();
  if (tid < 32) {  // lanes 0..31 of wave 0: softmax + top2 + partials
    const int m = tid;
    float pr[8], mx = -1e30f;
    for (int e = 0; e < 8; e++) { pr[e] = lg[m][e]; mx = fmaxf(mx, pr[e]); }
    float s = 0.f;
    for (int e = 0; e < 8; e++) { pr[e] = __expf(pr[e] - mx); s += pr[e]; }
    float inv = 1.f / s;
    for (int e = 0; e < 8; e++) pr[e] *= inv;
    int i0 = 0;
    for (int e = 1; e < 8; e++) if (pr[e] > pr[i0]) i0 = e;
    int i1 = (i0 == 0) ? 1 : 0;
    for (int e = 0; e < 8; e++) if (e != i0 && pr[e] > pr[i1]) i1 = e;
    const int t = t0 + m;
    ((uchar2*)(ws + WS_TOPKI))[t] = make_uchar2((unsigned char)i0, (unsigned char)i1);
    ((float*)(ws + WS_TOPKP))[2 * t] = pr[i0];
    ((float*)(ws + WS_TOPKP))[2 * t + 1] = pr[i1];
    float* ip = (float*)(ws + WS_IMP) + blockIdx.x * 8;
    int* cp = (int*)(ws + WS_CNTP) + blockIdx.x * 8;
    for (int e = 0; e < 8; e++) {
      float v = pr[e];
      for (int off = 16; off; off >>= 1) v += __shfl_down(v, off);  // lanes 0..31 only
      unsigned long long b0 = __ballot(i0 == e);   // high 32 bits are 0 (inactive)
      unsigned long long b1 = __ballot(i1 == e);
      if (tid == 0) { ip[e] = v; cp[e] = __popcll(b0) + __popcll(b1); }
    }
  }
}

// ---------------- finalize: running[], counts, padded prefix, tile table ----
__global__ void finalize_kernel(char* __restrict__ ws) {
  const int tid = threadIdx.x;
  if (tid < 8) {
    float s = 0.f; int c = 0;
    const float* ip = (const float*)(ws + WS_IMP);
    const int* cp = (const int*)(ws + WS_CNTP);
    for (int b = 0; b < 256; b++) { s += ip[b * 8 + tid]; c += cp[b * 8 + tid]; }
    float running = 1.0f;
    float blended = running + 0.1f * (s - running);
    ((float*)(ws + WS_RUN))[tid] = blended + 0.01f;
    ((int*)(ws + WS_CNT))[tid] = c;
    ((int*)(ws + WS_CNT2))[tid * 16] = 0;   // padded counters, 1 per cacheline
  }
  __syncthreads();
  if (tid == 0) {
    const int* cnt = (const int*)(ws + WS_CNT);
    int* offp = (int*)(ws + WS_OFFP);
    int* ttab = (int*)(ws + WS_TTAB);
    int o = 0, n = 0;
    for (int e = 0; e < 8; e++) {
      offp[e] = o;
      int tl = (cnt[e] + BM - 1) / BM;
      o += tl * BM;
      for (int r = 0; r < tl; r++) ttab[n++] = (e << 8) | r;
    }
    *((int*)(ws + WS_NTIL)) = n;
  }
}

// ------- build lists: wave-aggregated ballot ranks, 1 atomic/(wave,expert) --
__global__ __launch_bounds__(256) void build_lists(char* __restrict__ ws) {
  const int t = blockIdx.x * blockDim.x + threadIdx.x;
  const int lane = threadIdx.x & 63;
  const uchar2* ti = (const uchar2*)(ws + WS_TOPKI);
  const float* tp = (const float*)(ws + WS_TOPKP);
  const float* run = (const float*)(ws + WS_RUN);
  int* cnt2 = (int*)(ws + WS_CNT2);
  const int* offp = (const int*)(ws + WS_OFFP);
  int* ltok = (int*)(ws + WS_LTOK);
  float* lw = (float*)(ws + WS_LW);
  const uchar2 ee = ti[t];
  const int e0 = ee.x, e1 = ee.y;
  const float b0 = tp[2 * t] / run[e0], b1 = tp[2 * t + 1] / run[e1];
  const float inv = 1.f / (b0 + b1);
  const unsigned long long lt = (1ull << lane) - 1ull;
  int g0 = 0, g1 = 0;
#pragma unroll
  for (int e = 0; e < 8; e++) {
    unsigned long long m0 = __ballot(e0 == e);
    unsigned long long m1 = __ballot(e1 == e);
    const int c0 = __popcll(m0);
    const int ctot = c0 + __popcll(m1);
    int base = 0;
    if (lane == 0 && ctot) base = atomicAdd(&cnt2[e * 16], ctot);
    base = __shfl(base, 0);
    if (e0 == e) g0 = offp[e] + base + __popcll(m0 & lt);
    if (e1 == e) g1 = offp[e] + base + c0 + __popcll(m1 & lt);
  }
  ltok[g0] = t; lw[g0] = b0 * inv;
  ltok[g1] = t; lw[g1] = b1 * inv;
  // overlay: WS_TG[t] occupies exactly tp[2t..2t+1] which this thread has read
  ((int2*)(ws + WS_TG))[t] = make_int2(g0, g1);
}

// ======== pipelined GEMM core (shared pattern, counted vmcnt) ========
// Per iteration: ds_read frags(buf cur) -> lgkm0+bar -> STAGE(cur,t+2)
//                -> MFMA -> vmcnt(8)/vmcnt(0 tail) -> bar -> flip.
#define GEMM_PIPELINE(NK)                                                      \
  {                                                                            \
    /* prologue: stage tiles 0 and 1 */                                        \
    stage(0, 0);                                                               \
    stage(1, 1);                                                               \
    asm volatile("s_waitcnt vmcnt(8)" ::: "memory");                           \
    __builtin_amdgcn_sched_barrier(0);                                         \
    asm volatile("s_barrier" ::: "memory");                                    \
    int cur = 0;                                                               \
    for (int t = 0; t < (NK); ++t) {                                           \
      bf16x8 af[2][4], bg[2][4];                                               \
      const unsigned short* rA = &SB[cur][0][0];                               \
      const unsigned short* rB = &SB[cur][1][0];                               \
      _Pragma("unroll") for (int ks = 0; ks < 2; ks++) {                       \
        const int sl = ((ks * 4 + hi) ^ (fr & 7)) * 8;                         \
        _Pragma("unroll") for (int i = 0; i < 4; i++)                          \
            af[ks][i] = *(const bf16x8*)&rA[(wr + i * 16 + fr) * BK + sl];     \
        _Pragma("unroll") for (int j = 0; j < 4; j++)                          \
            bg[ks][j] = *(const bf16x8*)&rB[(wc + j * 16 + fr) * BK + sl];     \
      }                                                                        \
      asm volatile("s_waitcnt lgkmcnt(0)" ::: "memory"); /* my reads done */   \
      __builtin_amdgcn_sched_barrier(0);                                       \
      asm volatile("s_barrier" ::: "memory");            /* all reads done */  \
      if (t + 2 < (NK)) stage(cur, t + 2);                                     \
      __builtin_amdgcn_s_setprio(1);                                           \
      _Pragma("unroll") for (int ks = 0; ks < 2; ks++)                         \
          _Pragma("unroll") for (int i = 0; i < 4; i++)                        \
              _Pragma("unroll") for (int j = 0; j < 4; j++)                    \
                  acc[i][j] = __builtin_amdgcn_mfma_f32_16x16x32_bf16(         \
                      af[ks][i], bg[ks][j], acc[i][j], 0, 0, 0);               \
      __builtin_amdgcn_s_setprio(0);                                           \
      if (t + 2 < (NK)) {                                                      \
        asm volatile("s_waitcnt vmcnt(8)" ::: "memory"); /* t+1 landed */      \
      } else {                                                                 \
        asm volatile("s_waitcnt vmcnt(0)" ::: "memory"); /* tail drain */      \
      }                                                                        \
      __builtin_amdgcn_sched_barrier(0);                                       \
      asm volatile("s_barrier" ::: "memory");            /* t+1 ready */       \
      cur ^= 1;                                                                \
    }                                                                          \
  }

// ---------------- GEMM1: h = silu(x_gather @ w1_e^T), K=768 ----------------
__global__ __launch_bounds__(256) void gemm1_kernel(char* __restrict__ ws) {
  __shared__ unsigned short SB[2][2][BM * BK];  // 64KB: [dbuf][A/B][128][64]
  const int nt = *(const int*)(ws + WS_NTIL);
  // XCD-aware swizzle (T1): hw id -> logical id so each XCD owns a
  // contiguous chunk of (tile, n-block) space; w1_e then stays in its L2.
  const int nbx = IDIM / BN;                    // 16
  int bid = blockIdx.y * nbx + blockIdx.x;
  const int chunk = (nbx * MAXTILES) >> 3;      // 2176/8 = 272, bijective
  bid = (bid & 7) * chunk + (bid >> 3);
  const int bx = bid % nbx, by = bid / nbx;
  if (by >= nt) return;
  const int tile = ((const int*)(ws + WS_TTAB))[by];
  const int e = tile >> 8, rt = tile & 255;
  const int ce = ((const int*)(ws + WS_CNT))[e];
  const int base = ((const int*)(ws + WS_OFFP))[e];
  const int* __restrict__ ltok = (const int*)(ws + WS_LTOK);
  const unsigned short* __restrict__ xb = (const unsigned short*)(ws + WS_XB);
  const unsigned short* __restrict__ w1b =
      (const unsigned short*)(ws + WS_W1B) + (size_t)e * IDIM * HDIM;
  unsigned short* __restrict__ hb = (unsigned short*)(ws + WS_H);

  const int tid = threadIdx.x;
  const int lane = tid & 63, wave = tid >> 6;
  const int lr = tid >> 3;                               // staging row 0..31 (per chunk)
  const int ko_sw = ((tid & 7) ^ (lr & 7)) * 8;          // swizzled k-slot (source side)
  const int n0 = bx * BN;

  const unsigned short* ga[4];
  const unsigned short* gb[4];
#pragma unroll
  for (int c = 0; c < 4; c++) {
    int s = rt * BM + c * 32 + lr; s = (s < ce) ? s : (ce - 1);
    ga[c] = xb + (size_t)ltok[base + s] * HDIM + ko_sw;
    gb[c] = w1b + (size_t)(n0 + c * 32 + lr) * HDIM + ko_sw;
  }

  auto stage = [&](int buf, int kt) {
    unsigned short* dA = &SB[buf][0][wave * 512];
    unsigned short* dB = &SB[buf][1][wave * 512];
#pragma unroll
    for (int c = 0; c < 4; c++) {
      gload_lds16(ga[c] + kt * BK, dA + c * 2048);
      gload_lds16(gb[c] + kt * BK, dB + c * 2048);
    }
  };

  f32x4 acc[4][4];
#pragma unroll
  for (int i = 0; i < 4; i++)
#pragma unroll
    for (int j = 0; j < 4; j++) acc[i][j] = (f32x4){0.f, 0.f, 0.f, 0.f};

  const int wr = (wave >> 1) * 64, wc = (wave & 1) * 64;
  const int fr = lane & 15, hi = lane >> 4;

  GEMM_PIPELINE(HDIM / BK)

  const int rq = (lane >> 4) * 4;
#pragma unroll
  for (int i = 0; i < 4; i++) {
#pragma unroll
    for (int r = 0; r < 4; r++) {
      const int slot = rt * BM + wr + i * 16 + rq + r;
      unsigned short* hrow = hb + (size_t)(base + slot) * IDIM + n0 + wc;
#pragma unroll
      for (int j = 0; j < 4; j++) {
        float v = acc[i][j][r];
        float sv = v / (1.f + __expf(-v));
        hrow[j * 16 + fr] = f2bf(sv);
      }
    }
  }
}

// ---------------- GEMM2: sel[g] = lw[g] * (h @ w2_e^T) (bf16), K=2048 ------
__global__ __launch_bounds__(256) void gemm2_kernel(char* __restrict__ ws) {
  __shared__ unsigned short SB[2][2][BM * BK];  // 64KB
  const int nt = *(const int*)(ws + WS_NTIL);
  const int nbx = HDIM / BN;                    // 6
  int bid = blockIdx.y * nbx + blockIdx.x;
  const int chunk = (nbx * MAXTILES) >> 3;      // 816/8 = 102, bijective
  bid = (bid & 7) * chunk + (bid >> 3);
  const int bx = bid % nbx, by = bid / nbx;
  if (by >= nt) return;
  const int tile = ((const int*)(ws + WS_TTAB))[by];
  const int e = tile >> 8, rt = tile & 255;
  const int ce = ((const int*)(ws + WS_CNT))[e];
  const int base = ((const int*)(ws + WS_OFFP))[e];
  const float* __restrict__ lw = (const float*)(ws + WS_LW);
  const unsigned short* __restrict__ hb = (const unsigned short*)(ws + WS_H);
  const unsigned short* __restrict__ w2b =
      (const unsigned short*)(ws + WS_W2B) + (size_t)e * HDIM * IDIM;
  unsigned short* __restrict__ selb = (unsigned short*)(ws + WS_SEL);

  const int tid = threadIdx.x;
  const int lane = tid & 63, wave = tid >> 6;
  const int lr = tid >> 3;
  const int ko_sw = ((tid & 7) ^ (lr & 7)) * 8;
  const int n0 = bx * BN;

  const unsigned short* ga[4];
  const unsigned short* gb[4];
#pragma unroll
  for (int c = 0; c < 4; c++) {
    ga[c] = hb + (size_t)(base + rt * BM + c * 32 + lr) * IDIM + ko_sw;  // pad rows defined
    gb[c] = w2b + (size_t)(n0 + c * 32 + lr) * IDIM + ko_sw;
  }

  auto stage = [&](int buf, int kt) {
    unsigned short* dA = &SB[buf][0][wave * 512];
    unsigned short* dB = &SB[buf][1][wave * 512];
#pragma unroll
    for (int c = 0; c < 4; c++) {
      gload_lds16(ga[c] + kt * BK, dA + c * 2048);
      gload_lds16(gb[c] + kt * BK, dB + c * 2048);
    }
  };

  f32x4 acc[4][4];
#pragma unroll
  for (int i = 0; i < 4; i++)
#pragma unroll
    for (int j = 0; j < 4; j++) acc[i][j] = (f32x4){0.f, 0.f, 0.f, 0.f};

  const int wr = (wave >> 1) * 64, wc = (wave & 1) * 64;
  const int fr = lane & 15, hi = lane >> 4;

  GEMM_PIPELINE(IDIM / BK)

  const int rq = (lane >> 4) * 4;
#pragma unroll
  for (int i = 0; i < 4; i++) {
#pragma unroll
    for (int r = 0; r < 4; r++) {
      const int slot = rt * BM + wr + i * 16 + rq + r;
      if (slot < ce) {
        const int g = base + slot;
        const float w = lw[g];                      // weight pre-applied before bf16
        unsigned short* srow = selb + (size_t)g * HDIM + n0 + wc;
#pragma unroll
        for (int j = 0; j < 4; j++)
          srow[j * 16 + fr] = f2bf(w * acc[i][j][r]);
      }
    }
  }
}

// ---------------- combine: out[t] = sel[g0] + sel[g1] ----------------------
__global__ __launch_bounds__(192) void combine_kernel(const char* __restrict__ ws,
                                                      float* __restrict__ out) {
  const int t = blockIdx.x;
  const int c = threadIdx.x;                         // 192 threads: 4 floats each
  const int2 g = ((const int2*)(ws + WS_TG))[t];
  const unsigned short* selb = (const unsigned short*)(ws + WS_SEL);
  ushort4 a = *(const ushort4*)(selb + (size_t)g.x * HDIM + c * 4);
  ushort4 b = *(const ushort4*)(selb + (size_t)g.y * HDIM + c * 4);
  float4 o;
  o.x = bf2f(a.x) + bf2f(b.x);
  o.y = bf2f(a.y) + bf2f(b.y);
  o.z = bf2f(a.z) + bf2f(b.z);
  o.w = bf2f(a.w) + bf2f(b.w);
  ((float4*)out)[(size_t)t * (HDIM / 4) + c] = o;
}

extern "C" void kernel_launch(void* const* d_in, const int* in_sizes, int n_in,
                              void* d_out, int out_size, void* d_ws, size_t ws_size,
                              hipStream_t stream) {
  const float* x = (const float*)d_in[0];
  const float* rw = (const float*)d_in[1];
  const float* w1 = (const float*)d_in[2];
  const float* w2 = (const float*)d_in[3];
  float* out = (float*)d_out;
  char* ws = (char*)d_ws;

  if (ws_size < (size_t)WS_NEEDED) {  // diagnostic path: zeros
    hipMemsetAsync(d_out, 0, (size_t)out_size * sizeof(float), stream);
    return;
  }

  cvt_kernel<<<1024, 256, 0, stream>>>(x, (unsigned short*)(ws + WS_XB), NTOK * HDIM / 8);
  cvt_kernel<<<1024, 256, 0, stream>>>(w1, (unsigned short*)(ws + WS_W1B), NEXP * IDIM * HDIM / 8);
  cvt_kernel<<<1024, 256, 0, stream>>>(w2, (unsigned short*)(ws + WS_W2B), NEXP * HDIM * IDIM / 8);
  router_kernel<<<NTOK / 32, 256, 0, stream>>>(x, rw, ws);
  finalize_kernel<<<1, 64, 0, stream>>>(ws);
  build_lists<<<NTOK / 256, 256, 0, stream>>>(ws);
  gemm1_kernel<<<dim3(IDIM / BN, MAXTILES), 256, 0, stream>>>(ws);
  gemm2_kernel<<<dim3(HDIM / BN, MAXTILES), 256, 0, stream>>>(ws);
  combine_kernel<<<NTOK, 192, 0, stream>>>(ws, out);
}